// Round 1
// baseline (47.166 us; speedup 1.0000x reference)
//
#include <hip/hip_runtime.h>

#define MARGIN_F 0.1f

__global__ __launch_bounds__(256) void selfMarginLoss_kernel(
    const float* __restrict__ scores,
    const int* __restrict__ werRank,
    float* __restrict__ out,
    int B, int N) {

    const int lane = threadIdx.x & 63;
    const int waveInBlock = threadIdx.x >> 6;
    const int wavesPerBlock = blockDim.x >> 6;
    const int waveId = blockIdx.x * wavesPerBlock + waveInBlock;
    const int totalWaves = gridDim.x * wavesPerBlock;

    float acc = 0.0f;

    for (int g = waveId; g < B; g += totalWaves) {
        // lane i holds ranked[i] = scores[g*N + werRank[g*N + i]]
        float r = 0.0f;
        if (lane < N) {
            int rk = werRank[g * N + lane];
            r = scores[g * N + rk];
        }
        // per_i = sum_{j>i} max(ranked[j] - ranked[i] + margin, 0)
        float s = 0.0f;
        for (int j = 1; j < N; ++j) {
            float rj = __shfl(r, j, 64);   // uniform j: broadcast lane j's value
            if (lane < j) {
                float d = rj - r + MARGIN_F;
                if (d > 0.0f) s += d;
            }
        }
        if (lane < N) {
            int denom = N - 1 - lane;
            if (denom < 1) denom = 1;
            acc += s / (float)denom;
        }
    }

    // wave reduction (64 lanes)
    #pragma unroll
    for (int off = 32; off; off >>= 1)
        acc += __shfl_xor(acc, off, 64);

    __shared__ float partial[16];
    if (lane == 0) partial[waveInBlock] = acc;
    __syncthreads();

    if (threadIdx.x == 0) {
        float b = 0.0f;
        for (int w = 0; w < wavesPerBlock; ++w) b += partial[w];
        atomicAdd(out, b);
    }
}

extern "C" void kernel_launch(void* const* d_in, const int* in_sizes, int n_in,
                              void* d_out, int out_size, void* d_ws, size_t ws_size,
                              hipStream_t stream) {
    const float* scores  = (const float*)d_in[0];
    // d_in[1] = nBestIndex (uniform N, unused — reference uses werRank's shape)
    const int*   werRank = (const int*)d_in[2];
    float* out = (float*)d_out;

    const int B = in_sizes[1];                 // 16384 groups
    const int N = in_sizes[2] / in_sizes[1];   // 50 per group

    // d_out is poisoned before timing; zero it every call (capture-safe).
    hipMemsetAsync(d_out, 0, sizeof(float), stream);

    const int threads = 256;
    const int wavesPerBlock = threads / 64;
    int blocks = (B + 2 * wavesPerBlock - 1) / (2 * wavesPerBlock);  // ~2 groups/wave
    if (blocks > 2048) blocks = 2048;
    if (blocks < 1) blocks = 1;

    selfMarginLoss_kernel<<<blocks, threads, 0, stream>>>(scores, werRank, out, B, N);
}

// Round 2
// 16.864 us; speedup vs baseline: 2.7969x; 2.7969x over previous
//
#include <hip/hip_runtime.h>

constexpr int   NBEST  = 50;
constexpr float MARGIN = 0.1f;
constexpr int   GPB    = 64;          // groups per block (one per lane)
constexpr int   PAD    = NBEST + 1;   // 51: odd stride -> conflict-free LDS reads

// Each wave handles i in [LO,HI) for its lane's group. Fully unrolled,
// compile-time indices only (runtime-indexed arrays would spill to scratch).
template<int LO, int HI>
__device__ __forceinline__ float computeRange(const float* __restrict__ row) {
    constexpr int M = HI - LO;
    float rim[M];   // ranked[i] - margin
    float accs[M];
#pragma unroll
    for (int k = 0; k < M; ++k) {
        rim[k]  = row[LO + k] - MARGIN;
        accs[k] = 0.0f;
    }
#pragma unroll
    for (int j = LO + 1; j < NBEST; ++j) {
        float rj = row[j];               // one ds_read, reused for all i < j
#pragma unroll
        for (int k = 0; k < M; ++k) {
            if (LO + k < j)              // compile-time predicate
                accs[k] += fmaxf(rj - rim[k], 0.0f);
        }
    }
    float s = 0.0f;
#pragma unroll
    for (int k = 0; k < M; ++k)
        s += accs[k] * (1.0f / float(NBEST - 1 - (LO + k)));  // const-folded recip
    return s;
}

__global__ __launch_bounds__(256) void selfMarginLoss_kernel(
    const float* __restrict__ scores,
    const int*   __restrict__ werRank,
    float*       __restrict__ out,
    int B) {

    __shared__ float ranked[GPB * PAD];
    __shared__ float partial[4];

    const int tid   = threadIdx.x;
    const int gbase = blockIdx.x * GPB;
    const int nG    = min(GPB, B - gbase);
    const int total = nG * NBEST;
    const long base = (long)gbase * NBEST;

    // Stage ranked[g][i] = scores[g*N + werRank[g*N+i]] into LDS.
    // werRank read coalesced; scores gather stays inside each group's 200B window.
    for (int idx = tid; idx < total; idx += 256) {
        int g = idx / NBEST;
        int i = idx - g * NBEST;
        int rk = werRank[base + idx];
        ranked[g * PAD + i] = scores[base + g * NBEST + rk];
    }
    __syncthreads();

    const int lane = tid & 63;
    const int wave = tid >> 6;

    float acc = 0.0f;
    if (lane < nG) {
        const float* row = &ranked[lane * PAD];
        // Pair-balanced contiguous i-ranges: 322 / 308 / 319 / 276 pairs.
        if      (wave == 0) acc = computeRange< 0,  7>(row);
        else if (wave == 1) acc = computeRange< 7, 15>(row);
        else if (wave == 2) acc = computeRange<15, 26>(row);
        else                acc = computeRange<26, 49>(row);
    }

    // wave reduction (64 lanes)
#pragma unroll
    for (int off = 32; off; off >>= 1)
        acc += __shfl_xor(acc, off, 64);

    if (lane == 0) partial[wave] = acc;
    __syncthreads();

    if (tid == 0)
        atomicAdd(out, partial[0] + partial[1] + partial[2] + partial[3]);
}

extern "C" void kernel_launch(void* const* d_in, const int* in_sizes, int n_in,
                              void* d_out, int out_size, void* d_ws, size_t ws_size,
                              hipStream_t stream) {
    const float* scores  = (const float*)d_in[0];
    // d_in[1] = nBestIndex (uniform N, unused)
    const int*   werRank = (const int*)d_in[2];
    float* out = (float*)d_out;

    const int B = in_sizes[1];                 // 16384 groups

    // d_out is poisoned before timing; zero it every call (capture-safe).
    hipMemsetAsync(d_out, 0, sizeof(float), stream);

    int blocks = (B + GPB - 1) / GPB;          // 256 blocks -> 1 block/CU, 1 wave/SIMD
    selfMarginLoss_kernel<<<blocks, 256, 0, stream>>>(scores, werRank, out, B);
}

// Round 3
// 16.184 us; speedup vs baseline: 2.9144x; 1.0420x over previous
//
#include <hip/hip_runtime.h>

constexpr int   NBEST   = 50;
constexpr float MARGIN  = 0.1f;
constexpr int   GPB     = 64;          // groups per block (one per lane)
constexpr int   PAD     = NBEST + 1;   // 51: odd dword stride -> 2-way (free) LDS access
constexpr int   THREADS = 512;         // 8 waves -> 2 waves/SIMD
constexpr int   NWAVES  = THREADS / 64;

// Wave handles i in [LO,HI) for its lane's group. Fully unrolled, compile-time
// indices only (runtime-indexed register arrays would spill to scratch).
template<int LO, int HI>
__device__ __forceinline__ float computeRange(const float* __restrict__ row) {
    constexpr int M = HI - LO;
    float rim[M];   // ranked[i] - margin
    float accs[M];
#pragma unroll
    for (int k = 0; k < M; ++k) {
        rim[k]  = row[LO + k] - MARGIN;
        accs[k] = 0.0f;
    }
#pragma unroll
    for (int j = LO + 1; j < NBEST; ++j) {
        float rj = row[j];               // one ds_read, reused for all i < j
#pragma unroll
        for (int k = 0; k < M; ++k) {
            if (LO + k < j)              // compile-time predicate
                accs[k] += fmaxf(rj - rim[k], 0.0f);
        }
    }
    float s = 0.0f;
#pragma unroll
    for (int k = 0; k < M; ++k)
        s += accs[k] * (1.0f / float(NBEST - 1 - (LO + k)));  // const-folded recip
    return s;
}

__global__ __launch_bounds__(THREADS) void selfMarginLoss_kernel(
    const float* __restrict__ scores,
    const int*   __restrict__ werRank,
    float*       __restrict__ out,
    int B) {

    __shared__ float ranked[GPB * PAD];
    __shared__ float partial[NWAVES];

    const int  tid   = threadIdx.x;
    const int  gbase = blockIdx.x * GPB;
    const long base  = (long)gbase * NBEST;

    if (gbase + GPB <= B) {
        // Fast path: full block, compile-time trip counts, int4 werRank loads.
        constexpr int TOTAL = GPB * NBEST;   // 3200
        constexpr int NV4   = TOTAL / 4;     // 800 int4 vectors
        const int4* wr4 = (const int4*)(werRank + base);  // 16B-aligned (12800B/block)
#pragma unroll
        for (int it = 0; it < 2; ++it) {
            const int v = tid + it * THREADS;
            if (v < NV4) {
                int4 rk = wr4[v];
                int e0  = v * 4;
                int g   = e0 / NBEST;        // compile-strength-reduced
                int col = e0 - g * NBEST;
                int rks[4] = {rk.x, rk.y, rk.z, rk.w};
#pragma unroll
                for (int c = 0; c < 4; ++c) {
                    ranked[g * PAD + col] = scores[base + g * NBEST + rks[c]];
                    ++col;
                    if (col == NBEST) { col = 0; ++g; }   // carry, no division
                }
            }
        }
    } else {
        // Tail path (unused for B=16384 but kept correct).
        const int nG    = B - gbase;
        const int total = nG * NBEST;
        for (int idx = tid; idx < total; idx += THREADS) {
            int g  = idx / NBEST;
            int i  = idx - g * NBEST;
            int rk = werRank[base + idx];
            ranked[g * PAD + i] = scores[base + g * NBEST + rk];
        }
    }
    __syncthreads();

    const int lane = tid & 63;
    const int wave = tid >> 6;

    float acc = 0.0f;
    if (gbase + lane < B) {
        const float* row = &ranked[lane * PAD];
        // Pair-balanced contiguous i-ranges (pairs): 144/135/166/150/165/165/147/153.
        switch (wave) {
            case 0:  acc = computeRange< 0,  3>(row); break;
            case 1:  acc = computeRange< 3,  6>(row); break;
            case 2:  acc = computeRange< 6, 10>(row); break;
            case 3:  acc = computeRange<10, 14>(row); break;
            case 4:  acc = computeRange<14, 19>(row); break;
            case 5:  acc = computeRange<19, 25>(row); break;
            case 6:  acc = computeRange<25, 32>(row); break;
            default: acc = computeRange<32, 49>(row); break;
        }
    }

    // wave reduction (64 lanes)
#pragma unroll
    for (int off = 32; off; off >>= 1)
        acc += __shfl_xor(acc, off, 64);

    if (lane == 0) partial[wave] = acc;
    __syncthreads();

    if (tid == 0) {
        float b = 0.0f;
#pragma unroll
        for (int w = 0; w < NWAVES; ++w) b += partial[w];
        atomicAdd(out, b);
    }
}

extern "C" void kernel_launch(void* const* d_in, const int* in_sizes, int n_in,
                              void* d_out, int out_size, void* d_ws, size_t ws_size,
                              hipStream_t stream) {
    const float* scores  = (const float*)d_in[0];
    // d_in[1] = nBestIndex (uniform N, unused)
    const int*   werRank = (const int*)d_in[2];
    float* out = (float*)d_out;

    const int B = in_sizes[1];                 // 16384 groups

    // d_out is poisoned once before timing and atomicAdd would accumulate
    // across replays — zero it every call (capture-safe).
    hipMemsetAsync(d_out, 0, sizeof(float), stream);

    int blocks = (B + GPB - 1) / GPB;          // 256 blocks -> 1 block/CU, 8 waves each
    selfMarginLoss_kernel<<<blocks, THREADS, 0, stream>>>(scores, werRank, out, B);
}